// Round 1
// baseline (2138.911 us; speedup 1.0000x reference)
//
#include <hip/hip_runtime.h>
#include <hip/hip_bf16.h>
#include <cstdint>
#include <cstddef>

#define N_RAYS 262144
#define NR 32          // rays per block
#define THREADS 256
#define FSTRIDE 292    // feats row stride (floats): 292%32==4 -> conflict-free broadcast groups

// ---------- helpers ----------
__device__ __forceinline__ float bf_extract(const uint4& q, int i) {
    // i is compile-time constant under full unroll
    uint32_t w = ((const uint32_t*)&q)[i >> 1];
    uint32_t h = (i & 1) ? (w & 0xFFFF0000u) : (w << 16);
    return __uint_as_float(h);
}

__device__ __forceinline__ uint16_t f2bf_rne(float f) {
    uint32_t x = __float_as_uint(f);
    uint32_t r = x + 0x7FFFu + ((x >> 16) & 1u);
    return (uint16_t)(r >> 16);
}

__device__ __forceinline__ float sel4(const float4& p, int i) {
    float r = p.x;
    r = (i == 1) ? p.y : r;
    r = (i == 2) ? p.z : r;
    r = (i == 3) ? p.w : r;
    return r;
}

// ---------- transpose: [6][16][H][H] f32 -> [6][H][H][16] bf16 ----------
__global__ void transpose_kernel(const float* __restrict__ in,
                                 __hip_bfloat16* __restrict__ out, int H) {
    int idx = blockIdx.x * blockDim.x + threadIdx.x;
    int hh = H * H;
    int total = 6 * hh;
    if (idx >= total) return;
    int c = idx / hh;               // power-of-2 -> shift
    int rem = idx - c * hh;
    const float* ip = in + (size_t)c * 16 * hh + rem;
    uint32_t words[8];
    #pragma unroll
    for (int j = 0; j < 8; ++j) {
        uint16_t lo = f2bf_rne(ip[(size_t)(2 * j) * hh]);
        uint16_t hi = f2bf_rne(ip[(size_t)(2 * j + 1) * hh]);
        words[j] = (uint32_t)lo | ((uint32_t)hi << 16);
    }
    uint4* op = (uint4*)((uint16_t*)out + (size_t)idx * 16);
    op[0] = make_uint4(words[0], words[1], words[2], words[3]);
    op[1] = make_uint4(words[4], words[5], words[6], words[7]);
}

// ---------- fused gather + MLP ----------
template <bool USE_T>
__global__ __launch_bounds__(THREADS) void fused_kernel(
    const float4* __restrict__ ray,
    const float* __restrict__ g0, const float* __restrict__ g1,
    const float* __restrict__ g2,
    const __hip_bfloat16* __restrict__ gt,
    const float* __restrict__ weights1, const float* __restrict__ bias1,
    const float* __restrict__ weights2, const float* __restrict__ bias2,
    float* __restrict__ out) {
    __shared__ float4 s_ray[NR];
    __shared__ float s_feats[NR][FSTRIDE];

    int tid = threadIdx.x;
    int rbase = blockIdx.x * NR;
    if (tid < NR) s_ray[tid] = ray[rbase + tid];
    __syncthreads();

    // ---- phase A: gather + bilinear -> s_feats[r][0..287] ----
    for (int t = tid; t < NR * 36; t += THREADS) {
        int r = t / 36;
        int rem = t - r * 36;
        int interp = rem >> 1;
        int half = rem & 1;
        int level = (interp >= 12) ? 2 : ((interp >= 6) ? 1 : 0);
        int comb = interp - level * 6;
        int H = 128 << level;
        float4 p = s_ray[r];
        int c0 = (0x211000 >> (4 * comb)) & 0xF;   // 0,0,0,1,1,2
        int c1 = (0x332321 >> (4 * comb)) & 0xF;   // 1,2,3,2,3,3
        float u = sel4(p, c0) * (float)(H - 1);
        float v = sel4(p, c1) * (float)(H - 1);
        float u0f = fminf(fmaxf(floorf(u), 0.0f), (float)(H - 2));
        float v0f = fminf(fmaxf(floorf(v), 0.0f), (float)(H - 2));
        float wu = u - u0f, wv = v - v0f;
        int u0 = (int)u0f, v0 = (int)v0f;
        float w00 = (1.0f - wu) * (1.0f - wv);
        float w01 = (1.0f - wu) * wv;
        float w10 = wu * (1.0f - wv);
        float w11 = wu * wv;
        float f[8];
        if (USE_T) {
            size_t lvl_off = (level == 0) ? 0u : ((level == 1) ? 1572864u : 7864320u);
            const uint16_t* gp = (const uint16_t*)gt + lvl_off +
                                 (((size_t)comb * H + u0) * H + v0) * 16 + half * 8;
            uint4 a00 = *(const uint4*)gp;
            uint4 a01 = *(const uint4*)(gp + 16);
            uint4 a10 = *(const uint4*)(gp + (size_t)16 * H);
            uint4 a11 = *(const uint4*)(gp + (size_t)16 * H + 16);
            #pragma unroll
            for (int i = 0; i < 8; ++i) {
                f[i] = w00 * bf_extract(a00, i) + w01 * bf_extract(a01, i) +
                       w10 * bf_extract(a10, i) + w11 * bf_extract(a11, i);
            }
        } else {
            const float* gp = (level == 0) ? g0 : ((level == 1) ? g1 : g2);
            const float* base = gp + ((size_t)(comb * 16 + half * 8) * H + u0) * H + v0;
            #pragma unroll
            for (int i = 0; i < 8; ++i) {
                const float* q = base + (size_t)i * H * H;
                float a00 = q[0], a01 = q[1], a10 = q[H], a11 = q[H + 1];
                f[i] = w00 * a00 + w01 * a01 + w10 * a10 + w11 * a11;
            }
        }
        int fo = interp * 16 + half * 8;
        float* fp = &s_feats[r][fo];
        #pragma unroll
        for (int i = 0; i < 8; ++i) fp[i] = f[i];
    }
    __syncthreads();

    // ---- phase B: MLP ----
    int r = tid >> 3;
    int jg = tid & 7;
    int j0 = jg * 16;
    float acc[16];
    #pragma unroll
    for (int jj = 0; jj < 16; ++jj) acc[jj] = bias1[j0 + jj];

    const float* wp = weights1 + j0;
    for (int k = 0; k < 288; k += 4) {
        float4 fv = *(const float4*)&s_feats[r][k];
        #pragma unroll
        for (int kk = 0; kk < 4; ++kk) {
            const float4* wr = (const float4*)(wp + (size_t)(k + kk) * 128);
            float fk = (kk == 0) ? fv.x : ((kk == 1) ? fv.y : ((kk == 2) ? fv.z : fv.w));
            float4 wa = wr[0], wb = wr[1], wc = wr[2], wd = wr[3];
            acc[0]  += fk * wa.x; acc[1]  += fk * wa.y; acc[2]  += fk * wa.z; acc[3]  += fk * wa.w;
            acc[4]  += fk * wb.x; acc[5]  += fk * wb.y; acc[6]  += fk * wb.z; acc[7]  += fk * wb.w;
            acc[8]  += fk * wc.x; acc[9]  += fk * wc.y; acc[10] += fk * wc.z; acc[11] += fk * wc.w;
            acc[12] += fk * wd.x; acc[13] += fk * wd.y; acc[14] += fk * wd.z; acc[15] += fk * wd.w;
        }
    }

    float p0 = 0.f, p1 = 0.f, p2 = 0.f;
    #pragma unroll
    for (int jj = 0; jj < 16; ++jj) {
        float h = fmaxf(acc[jj], 0.0f);
        const float* w2r = weights2 + (size_t)(j0 + jj) * 3;
        p0 += h * w2r[0];
        p1 += h * w2r[1];
        p2 += h * w2r[2];
    }
    p0 += __shfl_xor(p0, 1); p0 += __shfl_xor(p0, 2); p0 += __shfl_xor(p0, 4);
    p1 += __shfl_xor(p1, 1); p1 += __shfl_xor(p1, 2); p1 += __shfl_xor(p1, 4);
    p2 += __shfl_xor(p2, 1); p2 += __shfl_xor(p2, 2); p2 += __shfl_xor(p2, 4);

    if (jg == 0) {
        float o0 = 1.0f / (1.0f + expf(-(p0 + bias2[0])));
        float o1 = 1.0f / (1.0f + expf(-(p1 + bias2[1])));
        float o2 = 1.0f / (1.0f + expf(-(p2 + bias2[2])));
        float* op = out + (size_t)(rbase + r) * 3;
        op[0] = o0; op[1] = o1; op[2] = o2;
    }
}

extern "C" void kernel_launch(void* const* d_in, const int* in_sizes, int n_in,
                              void* d_out, int out_size, void* d_ws, size_t ws_size,
                              hipStream_t stream) {
    const float4* ray = (const float4*)d_in[0];
    const float* g0 = (const float*)d_in[1];
    const float* g1 = (const float*)d_in[2];
    const float* g2 = (const float*)d_in[3];
    const float* w1 = (const float*)d_in[4];
    const float* b1 = (const float*)d_in[5];
    const float* w2 = (const float*)d_in[6];
    const float* b2 = (const float*)d_in[7];
    float* out = (float*)d_out;

    const size_t T_ELEMS = 33030144;           // 6*16*(128^2+256^2+512^2)
    bool use_t = ws_size >= T_ELEMS * 2;

    int nblocks = N_RAYS / NR;

    if (use_t) {
        __hip_bfloat16* wsb = (__hip_bfloat16*)d_ws;
        __hip_bfloat16* t0 = wsb;
        __hip_bfloat16* t1 = wsb + 1572864;    // 6*128*128*16
        __hip_bfloat16* t2 = wsb + 7864320;    // + 6*256*256*16
        {
            int total = 6 * 128 * 128;
            transpose_kernel<<<(total + 255) / 256, 256, 0, stream>>>(g0, t0, 128);
        }
        {
            int total = 6 * 256 * 256;
            transpose_kernel<<<(total + 255) / 256, 256, 0, stream>>>(g1, t1, 256);
        }
        {
            int total = 6 * 512 * 512;
            transpose_kernel<<<(total + 255) / 256, 256, 0, stream>>>(g2, t2, 512);
        }
        fused_kernel<true><<<nblocks, THREADS, 0, stream>>>(
            ray, g0, g1, g2, (const __hip_bfloat16*)wsb, w1, b1, w2, b2, out);
    } else {
        fused_kernel<false><<<nblocks, THREADS, 0, stream>>>(
            ray, g0, g1, g2, nullptr, w1, b1, w2, b2, out);
    }
}